// Round 1
// baseline (308.406 us; speedup 1.0000x reference)
//
#include <hip/hip_runtime.h>

#define Bn 2
#define Tn 2048
#define Dn 1024
#define Hn 16
#define HDn 64
#define Mn 4096

typedef __attribute__((ext_vector_type(8))) short bf16x8;
typedef __attribute__((ext_vector_type(4))) float f32x4;

__device__ __forceinline__ unsigned short f2bf(float f) {
  unsigned int x = __builtin_bit_cast(unsigned int, f);
  x += 0x7FFFu + ((x >> 16) & 1u);   // round-to-nearest-even
  return (unsigned short)(x >> 16);
}

__device__ __forceinline__ void gload_lds16(const void* g, void* l) {
  __builtin_amdgcn_global_load_lds(
      (const __attribute__((address_space(1))) unsigned int*)g,
      (__attribute__((address_space(3))) unsigned int*)l,
      16, 0, 0);
}

// ---------------- f32 -> bf16 convert (x), vectorized ----------------
__global__ __launch_bounds__(256) void cvt_bf16(const float* __restrict__ in,
                                                unsigned short* __restrict__ out) {
  int i = (blockIdx.x * 256 + threadIdx.x) * 4;
  float4 v = *reinterpret_cast<const float4*>(in + i);
  ushort4 o;
  o.x = f2bf(v.x); o.y = f2bf(v.y); o.z = f2bf(v.z); o.w = f2bf(v.w);
  *reinterpret_cast<ushort4*>(out + i) = o;
}

// ---------------- W[k][n] f32 -> WT[n][k] bf16, LDS-tiled ----------------
__global__ __launch_bounds__(256) void transpose_bf16(const float* __restrict__ W,
                                                      unsigned short* __restrict__ WT) {
  __shared__ float tile[32][33];
  int n0 = blockIdx.x * 32, k0 = blockIdx.y * 32;
  int tx = threadIdx.x, ty = threadIdx.y;   // 32 x 8
#pragma unroll
  for (int r = ty; r < 32; r += 8)
    tile[r][tx] = W[(size_t)(k0 + r) * Dn + n0 + tx];
  __syncthreads();
#pragma unroll
  for (int r = ty; r < 32; r += 8)
    WT[(size_t)(n0 + r) * Dn + k0 + tx] = f2bf(tile[tx][r]);
}

// ---------------- QKV projection GEMM: q/k [b,h,t,hd], v transposed [b,h,hd,t] ----------------
__global__ __launch_bounds__(256) void gemm_qkv(const unsigned short* __restrict__ A,   // x bf16 [4096][1024]
                                                const unsigned short* __restrict__ WTall, // 3+1 x [1024][1024]
                                                unsigned short* __restrict__ qb,
                                                unsigned short* __restrict__ kb,
                                                unsigned short* __restrict__ vtb) {
  const int m0 = blockIdx.x * 128;
  const int n0 = blockIdx.y * 128;
  const int z  = blockIdx.z;
  const unsigned short* BT = WTall + (size_t)z * 1048576;

  __shared__ unsigned short As[128 * 32];
  __shared__ unsigned short Bs[128 * 32];

  const int tid  = threadIdx.x;
  const int lane = tid & 63;
  const int wv   = tid >> 6;
  const int wr   = wv >> 1, wc = wv & 1;
  const int l15  = lane & 15, lg = lane >> 4;

  f32x4 acc[4][4];
#pragma unroll
  for (int mi = 0; mi < 4; ++mi)
#pragma unroll
    for (int ni = 0; ni < 4; ++ni)
      acc[mi][ni] = (f32x4){0.f, 0.f, 0.f, 0.f};

  for (int kt = 0; kt < 32; ++kt) {
#pragma unroll
    for (int it = 0; it < 2; ++it) {
      int e = (it * 256 + tid) * 8;
      int r = e >> 5, c = e & 31;
      gload_lds16(A  + (size_t)(m0 + r) * Dn + kt * 32 + c,
                  (char*)As + it * 4096 + wv * 1024);
      gload_lds16(BT + (size_t)(n0 + r) * Dn + kt * 32 + c,
                  (char*)Bs + it * 4096 + wv * 1024);
    }
    __syncthreads();

    bf16x8 af[4], bf[4];
#pragma unroll
    for (int mi = 0; mi < 4; ++mi) {
      int row = wr * 64 + mi * 16 + l15;
      af[mi] = *reinterpret_cast<const bf16x8*>(&As[row * 32 + lg * 8]);
    }
#pragma unroll
    for (int ni = 0; ni < 4; ++ni) {
      int row = wc * 64 + ni * 16 + l15;
      bf[ni] = *reinterpret_cast<const bf16x8*>(&Bs[row * 32 + lg * 8]);
    }
#pragma unroll
    for (int mi = 0; mi < 4; ++mi)
#pragma unroll
      for (int ni = 0; ni < 4; ++ni)
        acc[mi][ni] = __builtin_amdgcn_mfma_f32_16x16x32_bf16(af[mi], bf[ni], acc[mi][ni], 0, 0, 0);
    __syncthreads();
  }

  unsigned short* dst = (z == 0) ? qb : (z == 1) ? kb : vtb;
#pragma unroll
  for (int mi = 0; mi < 4; ++mi)
#pragma unroll
    for (int ni = 0; ni < 4; ++ni)
#pragma unroll
      for (int j = 0; j < 4; ++j) {
        int row = m0 + wr * 64 + mi * 16 + (lg << 2) + j;   // token index bt
        int col = n0 + wc * 64 + ni * 16 + l15;             // feature index
        int b = row >> 11, t = row & (Tn - 1);
        int h = col >> 6,  hd = col & 63;
        size_t idx = (z == 2)
          ? ((size_t)((b * Hn + h) * HDn + hd)) * Tn + t    // vT [b,h,hd,t]
          : ((size_t)(b * Hn + h) * Tn + t) * HDn + hd;     // q/k [b,h,t,hd]
        dst[idx] = f2bf(acc[mi][ni][j]);
      }
}

// ---------------- output projection GEMM + bias -> f32 ----------------
__global__ __launch_bounds__(256) void gemm_out(const unsigned short* __restrict__ A,   // ctx bf16 [4096][1024]
                                                const unsigned short* __restrict__ BT,  // WoT bf16 [1024][1024]
                                                const float* __restrict__ bias,
                                                float* __restrict__ out) {
  const int m0 = blockIdx.x * 128;
  const int n0 = blockIdx.y * 128;

  __shared__ unsigned short As[128 * 32];
  __shared__ unsigned short Bs[128 * 32];

  const int tid  = threadIdx.x;
  const int lane = tid & 63;
  const int wv   = tid >> 6;
  const int wr   = wv >> 1, wc = wv & 1;
  const int l15  = lane & 15, lg = lane >> 4;

  f32x4 acc[4][4];
#pragma unroll
  for (int mi = 0; mi < 4; ++mi)
#pragma unroll
    for (int ni = 0; ni < 4; ++ni)
      acc[mi][ni] = (f32x4){0.f, 0.f, 0.f, 0.f};

  for (int kt = 0; kt < 32; ++kt) {
#pragma unroll
    for (int it = 0; it < 2; ++it) {
      int e = (it * 256 + tid) * 8;
      int r = e >> 5, c = e & 31;
      gload_lds16(A  + (size_t)(m0 + r) * Dn + kt * 32 + c,
                  (char*)As + it * 4096 + wv * 1024);
      gload_lds16(BT + (size_t)(n0 + r) * Dn + kt * 32 + c,
                  (char*)Bs + it * 4096 + wv * 1024);
    }
    __syncthreads();

    bf16x8 af[4], bf[4];
#pragma unroll
    for (int mi = 0; mi < 4; ++mi) {
      int row = wr * 64 + mi * 16 + l15;
      af[mi] = *reinterpret_cast<const bf16x8*>(&As[row * 32 + lg * 8]);
    }
#pragma unroll
    for (int ni = 0; ni < 4; ++ni) {
      int row = wc * 64 + ni * 16 + l15;
      bf[ni] = *reinterpret_cast<const bf16x8*>(&Bs[row * 32 + lg * 8]);
    }
#pragma unroll
    for (int mi = 0; mi < 4; ++mi)
#pragma unroll
      for (int ni = 0; ni < 4; ++ni)
        acc[mi][ni] = __builtin_amdgcn_mfma_f32_16x16x32_bf16(af[mi], bf[ni], acc[mi][ni], 0, 0, 0);
    __syncthreads();
  }

#pragma unroll
  for (int mi = 0; mi < 4; ++mi)
#pragma unroll
    for (int ni = 0; ni < 4; ++ni)
#pragma unroll
      for (int j = 0; j < 4; ++j) {
        int row = m0 + wr * 64 + mi * 16 + (lg << 2) + j;
        int col = n0 + wc * 64 + ni * 16 + l15;
        out[(size_t)row * Dn + col] = acc[mi][ni][j] + bias[col];
      }
}

// ---------------- flash attention, causal, one wave = 16 q rows ----------------
__global__ __launch_bounds__(64) void attn(const unsigned short* __restrict__ q,
                                           const unsigned short* __restrict__ k,
                                           const unsigned short* __restrict__ vT,
                                           unsigned short* __restrict__ ctx) {
  __shared__ unsigned short p_lds[16 * 32];

  const int lane = threadIdx.x & 63;
  const int l15 = lane & 15, lg = lane >> 4;
  const int bh = blockIdx.y;              // b*16 + h
  const int b = bh >> 4, h = bh & 15;
  const int qbase = blockIdx.x * 16;

  const unsigned short* qh = q  + (size_t)bh * Tn * HDn;
  const unsigned short* kh = k  + (size_t)bh * Tn * HDn;
  const unsigned short* vh = vT + (size_t)bh * HDn * Tn;

  // Q A-fragments (16 rows x 64 hd = 2 K-chunks of 32)
  bf16x8 aq[2];
#pragma unroll
  for (int c = 0; c < 2; ++c)
    aq[c] = *reinterpret_cast<const bf16x8*>(qh + (size_t)(qbase + l15) * HDn + c * 32 + lg * 8);

  f32x4 oacc[4];
#pragma unroll
  for (int n = 0; n < 4; ++n) oacc[n] = (f32x4){0.f, 0.f, 0.f, 0.f};
  float mrow[4], lrow[4];
#pragma unroll
  for (int j = 0; j < 4; ++j) { mrow[j] = -INFINITY; lrow[j] = 0.f; }

  const int nkt = (qbase + 16 + 31) >> 5;
  for (int kt = 0; kt < nkt; ++kt) {
    const int k0 = kt * 32;

    // S = Q K^T  (16 x 32), two 16-col halves
    f32x4 s[2];
#pragma unroll
    for (int half = 0; half < 2; ++half) {
      s[half] = (f32x4){0.f, 0.f, 0.f, 0.f};
      const unsigned short* kr = kh + (size_t)(k0 + half * 16 + l15) * HDn + lg * 8;
      bf16x8 bk0 = *reinterpret_cast<const bf16x8*>(kr);
      bf16x8 bk1 = *reinterpret_cast<const bf16x8*>(kr + 32);
      s[half] = __builtin_amdgcn_mfma_f32_16x16x32_bf16(aq[0], bk0, s[half], 0, 0, 0);
      s[half] = __builtin_amdgcn_mfma_f32_16x16x32_bf16(aq[1], bk1, s[half], 0, 0, 0);
    }

    // online softmax per q-row (4 rows per lane, reduce across 16-lane group)
#pragma unroll
    for (int j = 0; j < 4; ++j) {
      int qg = qbase + (lg << 2) + j;
      float s0 = s[0][j] * 0.125f;
      float s1 = s[1][j] * 0.125f;
      if (k0 + l15 > qg)      s0 = -INFINITY;
      if (k0 + 16 + l15 > qg) s1 = -INFINITY;
      float mx = fmaxf(s0, s1);
#pragma unroll
      for (int d = 1; d < 16; d <<= 1) mx = fmaxf(mx, __shfl_xor(mx, d));
      float mnew = fmaxf(mrow[j], mx);
      float alpha = __expf(mrow[j] - mnew);
      float p0 = __expf(s0 - mnew);
      float p1 = __expf(s1 - mnew);
      float rs = p0 + p1;
#pragma unroll
      for (int d = 1; d < 16; d <<= 1) rs += __shfl_xor(rs, d);
      lrow[j] = lrow[j] * alpha + rs;
      mrow[j] = mnew;
#pragma unroll
      for (int n = 0; n < 4; ++n) oacc[n][j] *= alpha;
      int prow = (lg << 2) + j;
      p_lds[(prow << 5) + l15]      = f2bf(p0);
      p_lds[(prow << 5) + 16 + l15] = f2bf(p1);
    }

    // P A-fragment from LDS (within-wave dependency, compiler orders via lgkmcnt)
    bf16x8 pa = *reinterpret_cast<const bf16x8*>(&p_lds[l15 * 32 + lg * 8]);

    // O += P V : V B-operand = vT rows [hd][t]
#pragma unroll
    for (int n = 0; n < 4; ++n) {
      bf16x8 bv = *reinterpret_cast<const bf16x8*>(vh + (size_t)(n * 16 + l15) * Tn + k0 + lg * 8);
      oacc[n] = __builtin_amdgcn_mfma_f32_16x16x32_bf16(pa, bv, oacc[n], 0, 0, 0);
    }
  }

  // write ctx [bt][D] bf16
#pragma unroll
  for (int n = 0; n < 4; ++n)
#pragma unroll
    for (int j = 0; j < 4; ++j) {
      int qg = qbase + (lg << 2) + j;
      int hd = n * 16 + l15;
      ctx[(size_t)(b * Tn + qg) * Dn + h * HDn + hd] = f2bf(oacc[n][j] / lrow[j]);
    }
}

extern "C" void kernel_launch(void* const* d_in, const int* in_sizes, int n_in,
                              void* d_out, int out_size, void* d_ws, size_t ws_size,
                              hipStream_t stream) {
  const float* x  = (const float*)d_in[0];
  const float* Wq = (const float*)d_in[1];
  const float* Wk = (const float*)d_in[2];
  const float* Wv = (const float*)d_in[3];
  const float* Wo = (const float*)d_in[4];
  const float* bo = (const float*)d_in[5];
  float* out = (float*)d_out;

  unsigned short* ws  = (unsigned short*)d_ws;
  unsigned short* xbf = ws;                  // 4194304 elems
  unsigned short* wT  = ws + 4194304;        // 4 x 1048576 (Wq,Wk,Wv,Wo transposed)
  unsigned short* qb  = ws + 8388608;        // 4194304
  unsigned short* kb  = ws + 12582912;       // 4194304
  unsigned short* vtb = ws + 16777216;       // 4194304 (transposed [b,h,hd,t])
  unsigned short* ctx = ws + 20971520;       // 4194304

  cvt_bf16<<<4096, 256, 0, stream>>>(x, xbf);
  dim3 tb(32, 8);
  transpose_bf16<<<dim3(32, 32), tb, 0, stream>>>(Wq, wT);
  transpose_bf16<<<dim3(32, 32), tb, 0, stream>>>(Wk, wT + 1048576);
  transpose_bf16<<<dim3(32, 32), tb, 0, stream>>>(Wv, wT + 2097152);
  transpose_bf16<<<dim3(32, 32), tb, 0, stream>>>(Wo, wT + 3145728);

  gemm_qkv<<<dim3(32, 8, 3), 256, 0, stream>>>(xbf, wT, qb, kb, vtb);
  attn<<<dim3(128, 32), 64, 0, stream>>>(qb, kb, vtb, ctx);
  gemm_out<<<dim3(32, 8), 256, 0, stream>>>(ctx, wT + 3145728, bo, out);
}

// Round 2
// 180.664 us; speedup vs baseline: 1.7071x; 1.7071x over previous
//
#include <hip/hip_runtime.h>

#define Bn 2
#define Tn 2048
#define Dn 1024
#define Hn 16
#define HDn 64
#define Mn 4096

typedef __attribute__((ext_vector_type(8))) short bf16x8;
typedef __attribute__((ext_vector_type(4))) float f32x4;

__device__ __forceinline__ unsigned short f2bf(float f) {
  unsigned int x = __builtin_bit_cast(unsigned int, f);
  x += 0x7FFFu + ((x >> 16) & 1u);   // round-to-nearest-even
  return (unsigned short)(x >> 16);
}

__device__ __forceinline__ void gload_lds16(const void* g, void* l) {
  __builtin_amdgcn_global_load_lds(
      (const __attribute__((address_space(1))) unsigned int*)g,
      (__attribute__((address_space(3))) unsigned int*)l,
      16, 0, 0);
}

// ---------------- f32 -> bf16 convert (x), vectorized ----------------
__global__ __launch_bounds__(256) void cvt_bf16(const float* __restrict__ in,
                                                unsigned short* __restrict__ out) {
  int i = (blockIdx.x * 256 + threadIdx.x) * 4;
  float4 v = *reinterpret_cast<const float4*>(in + i);
  ushort4 o;
  o.x = f2bf(v.x); o.y = f2bf(v.y); o.z = f2bf(v.z); o.w = f2bf(v.w);
  *reinterpret_cast<ushort4*>(out + i) = o;
}

// ---------------- W[k][n] f32 -> WT[n][k] bf16, LDS-tiled ----------------
__global__ __launch_bounds__(256) void transpose_bf16(const float* __restrict__ W,
                                                      unsigned short* __restrict__ WT) {
  __shared__ float tile[32][33];
  int n0 = blockIdx.x * 32, k0 = blockIdx.y * 32;
  int tx = threadIdx.x, ty = threadIdx.y;   // 32 x 8
#pragma unroll
  for (int r = ty; r < 32; r += 8)
    tile[r][tx] = W[(size_t)(k0 + r) * Dn + n0 + tx];
  __syncthreads();
#pragma unroll
  for (int r = ty; r < 32; r += 8)
    WT[(size_t)(n0 + r) * Dn + k0 + tx] = f2bf(tile[tx][r]);
}

// ---------------- QKV projection GEMM: q/k [b,h,t,hd], v transposed [b,h,hd,t] ----------------
__global__ __launch_bounds__(256) void gemm_qkv(const unsigned short* __restrict__ A,
                                                const unsigned short* __restrict__ WTall,
                                                unsigned short* __restrict__ qb,
                                                unsigned short* __restrict__ kb,
                                                unsigned short* __restrict__ vtb) {
  const int m0 = blockIdx.x * 128;
  const int n0 = blockIdx.y * 128;
  const int z  = blockIdx.z;
  const unsigned short* BT = WTall + (size_t)z * 1048576;

  __shared__ unsigned short As[128 * 32];
  __shared__ unsigned short Bs[128 * 32];

  const int tid  = threadIdx.x;
  const int lane = tid & 63;
  const int wv   = tid >> 6;
  const int wr   = wv >> 1, wc = wv & 1;
  const int l15  = lane & 15, lg = lane >> 4;

  f32x4 acc[4][4];
#pragma unroll
  for (int mi = 0; mi < 4; ++mi)
#pragma unroll
    for (int ni = 0; ni < 4; ++ni)
      acc[mi][ni] = (f32x4){0.f, 0.f, 0.f, 0.f};

  for (int kt = 0; kt < 32; ++kt) {
#pragma unroll
    for (int it = 0; it < 2; ++it) {
      int e = (it * 256 + tid) * 8;
      int r = e >> 5, c = e & 31;
      gload_lds16(A  + (size_t)(m0 + r) * Dn + kt * 32 + c,
                  (char*)As + it * 4096 + wv * 1024);
      gload_lds16(BT + (size_t)(n0 + r) * Dn + kt * 32 + c,
                  (char*)Bs + it * 4096 + wv * 1024);
    }
    __syncthreads();

    bf16x8 af[4], bf[4];
#pragma unroll
    for (int mi = 0; mi < 4; ++mi) {
      int row = wr * 64 + mi * 16 + l15;
      af[mi] = *reinterpret_cast<const bf16x8*>(&As[row * 32 + lg * 8]);
    }
#pragma unroll
    for (int ni = 0; ni < 4; ++ni) {
      int row = wc * 64 + ni * 16 + l15;
      bf[ni] = *reinterpret_cast<const bf16x8*>(&Bs[row * 32 + lg * 8]);
    }
#pragma unroll
    for (int mi = 0; mi < 4; ++mi)
#pragma unroll
      for (int ni = 0; ni < 4; ++ni)
        acc[mi][ni] = __builtin_amdgcn_mfma_f32_16x16x32_bf16(af[mi], bf[ni], acc[mi][ni], 0, 0, 0);
    __syncthreads();
  }

  unsigned short* dst = (z == 0) ? qb : (z == 1) ? kb : vtb;
#pragma unroll
  for (int mi = 0; mi < 4; ++mi)
#pragma unroll
    for (int ni = 0; ni < 4; ++ni)
#pragma unroll
      for (int j = 0; j < 4; ++j) {
        int row = m0 + wr * 64 + mi * 16 + (lg << 2) + j;
        int col = n0 + wc * 64 + ni * 16 + l15;
        int b = row >> 11, t = row & (Tn - 1);
        int h = col >> 6,  hd = col & 63;
        size_t idx = (z == 2)
          ? ((size_t)((b * Hn + h) * HDn + hd)) * Tn + t
          : ((size_t)(b * Hn + h) * Tn + t) * HDn + hd;
        dst[idx] = f2bf(acc[mi][ni][j]);
      }
}

// ---------------- output projection GEMM + bias -> f32 ----------------
__global__ __launch_bounds__(256) void gemm_out(const unsigned short* __restrict__ A,
                                                const unsigned short* __restrict__ BT,
                                                const float* __restrict__ bias,
                                                float* __restrict__ out) {
  const int m0 = blockIdx.x * 128;
  const int n0 = blockIdx.y * 128;

  __shared__ unsigned short As[128 * 32];
  __shared__ unsigned short Bs[128 * 32];

  const int tid  = threadIdx.x;
  const int lane = tid & 63;
  const int wv   = tid >> 6;
  const int wr   = wv >> 1, wc = wv & 1;
  const int l15  = lane & 15, lg = lane >> 4;

  f32x4 acc[4][4];
#pragma unroll
  for (int mi = 0; mi < 4; ++mi)
#pragma unroll
    for (int ni = 0; ni < 4; ++ni)
      acc[mi][ni] = (f32x4){0.f, 0.f, 0.f, 0.f};

  for (int kt = 0; kt < 32; ++kt) {
#pragma unroll
    for (int it = 0; it < 2; ++it) {
      int e = (it * 256 + tid) * 8;
      int r = e >> 5, c = e & 31;
      gload_lds16(A  + (size_t)(m0 + r) * Dn + kt * 32 + c,
                  (char*)As + it * 4096 + wv * 1024);
      gload_lds16(BT + (size_t)(n0 + r) * Dn + kt * 32 + c,
                  (char*)Bs + it * 4096 + wv * 1024);
    }
    __syncthreads();

    bf16x8 af[4], bf[4];
#pragma unroll
    for (int mi = 0; mi < 4; ++mi) {
      int row = wr * 64 + mi * 16 + l15;
      af[mi] = *reinterpret_cast<const bf16x8*>(&As[row * 32 + lg * 8]);
    }
#pragma unroll
    for (int ni = 0; ni < 4; ++ni) {
      int row = wc * 64 + ni * 16 + l15;
      bf[ni] = *reinterpret_cast<const bf16x8*>(&Bs[row * 32 + lg * 8]);
    }
#pragma unroll
    for (int mi = 0; mi < 4; ++mi)
#pragma unroll
      for (int ni = 0; ni < 4; ++ni)
        acc[mi][ni] = __builtin_amdgcn_mfma_f32_16x16x32_bf16(af[mi], bf[ni], acc[mi][ni], 0, 0, 0);
    __syncthreads();
  }

#pragma unroll
  for (int mi = 0; mi < 4; ++mi)
#pragma unroll
    for (int ni = 0; ni < 4; ++ni)
#pragma unroll
      for (int j = 0; j < 4; ++j) {
        int row = m0 + wr * 64 + mi * 16 + (lg << 2) + j;
        int col = n0 + wc * 64 + ni * 16 + l15;
        out[(size_t)row * Dn + col] = acc[mi][ni][j] + bias[col];
      }
}

// ---------------- flash attention v2: 4 waves x 32 q-rows, KVBLK=64, LDS dbuf ----------------
// grid: 1-D, 512 blocks. head = bid % 32  -> all blocks of one head on XCD head%8.
// qb = 15 - bid/32 (heavy q-blocks dispatched first).
__global__ __launch_bounds__(256) void attn2(const unsigned short* __restrict__ q,
                                             const unsigned short* __restrict__ k,
                                             const unsigned short* __restrict__ vT,
                                             unsigned short* __restrict__ ctx) {
  __shared__ unsigned short Ks[2][4096];   // [key][hd], key-col-swizzled
  __shared__ unsigned short Vs[2][4096];   // [hd][key], key-col-swizzled
  __shared__ unsigned short Ps[4][2048];   // per-wave P [32][64], col-swizzled

  const int tid  = threadIdx.x;
  const int lane = tid & 63;
  const int wv   = tid >> 6;
  const int l15  = lane & 15, lg = lane >> 4;

  const int bid  = blockIdx.x;
  const int head = bid & 31;
  const int qb   = 15 - (bid >> 5);
  const int qbase = qb * 128;
  const int b = head >> 4, h = head & 15;

  const unsigned short* qh = q  + (size_t)head * Tn * HDn;
  const unsigned short* kh = k  + (size_t)head * Tn * HDn;
  const unsigned short* vh = vT + (size_t)head * HDn * Tn;

  const int qmin = qbase + wv * 32;
  const int qmax = qmin + 31;

  // Q fragments: 32 rows x 64 hd -> A-frags [mi][kc]
  bf16x8 aq[2][2];
#pragma unroll
  for (int mi = 0; mi < 2; ++mi)
#pragma unroll
    for (int kc = 0; kc < 2; ++kc)
      aq[mi][kc] = *reinterpret_cast<const bf16x8*>(
          qh + (size_t)(qmin + mi * 16 + l15) * HDn + kc * 32 + lg * 8);

  f32x4 oacc[2][4];
#pragma unroll
  for (int mi = 0; mi < 2; ++mi)
#pragma unroll
    for (int n = 0; n < 4; ++n) oacc[mi][n] = (f32x4){0.f, 0.f, 0.f, 0.f};
  float mrow[2][4], lrow[2][4];
#pragma unroll
  for (int mi = 0; mi < 2; ++mi)
#pragma unroll
    for (int j = 0; j < 4; ++j) { mrow[mi][j] = -INFINITY; lrow[mi][j] = 0.f; }

  // stage one 64-key tile of K and V into LDS buf (source pre-swizzled: elem col ^= (row&7)<<3)
  auto stage = [&](int buf, int k0) {
#pragma unroll
    for (int it = 0; it < 2; ++it) {
      int o = (it * 256 + tid) * 8;                 // elem offset in 64x64 tile
      int row = o >> 6;
      int col = (o & 63) ^ ((row & 7) << 3);
      gload_lds16(kh + (size_t)(k0 + row) * HDn + col,
                  (char*)&Ks[buf][0] + (it * 2048 + wv * 512) * 2);
      gload_lds16(vh + (size_t)row * Tn + k0 + col,
                  (char*)&Vs[buf][0] + (it * 2048 + wv * 512) * 2);
    }
  };

  const int nkt = (qbase + 128 + 63) >> 6;
  stage(0, 0);
  __syncthreads();

  for (int kt = 0; kt < nkt; ++kt) {
    const int buf = kt & 1;
    const int k0  = kt << 6;
    if (kt + 1 < nkt) stage(buf ^ 1, (kt + 1) << 6);

    if (k0 <= qmax) {
      // ---- S = Q K^T : 32 x 64 ----
      f32x4 s[2][4];
#pragma unroll
      for (int mi = 0; mi < 2; ++mi)
#pragma unroll
        for (int ci = 0; ci < 4; ++ci) s[mi][ci] = (f32x4){0.f, 0.f, 0.f, 0.f};
#pragma unroll
      for (int ci = 0; ci < 4; ++ci) {
        int row = ci * 16 + l15;
#pragma unroll
        for (int kc = 0; kc < 2; ++kc) {
          bf16x8 bk = *reinterpret_cast<const bf16x8*>(
              &Ks[buf][row * 64 + ((kc * 32 + lg * 8) ^ ((l15 & 7) << 3))]);
          s[0][ci] = __builtin_amdgcn_mfma_f32_16x16x32_bf16(aq[0][kc], bk, s[0][ci], 0, 0, 0);
          s[1][ci] = __builtin_amdgcn_mfma_f32_16x16x32_bf16(aq[1][kc], bk, s[1][ci], 0, 0, 0);
        }
      }

      const bool needmask = (k0 + 63 > qmin);
      // ---- online softmax, per lane: 8 rows x 4 col-chunks ----
#pragma unroll
      for (int mi = 0; mi < 2; ++mi)
#pragma unroll
        for (int j = 0; j < 4; ++j) {
          int qrow = qmin + mi * 16 + lg * 4 + j;
          float sv[4];
#pragma unroll
          for (int ci = 0; ci < 4; ++ci) {
            float v = s[mi][ci][j] * 0.125f;
            if (needmask && (k0 + ci * 16 + l15 > qrow)) v = -INFINITY;
            sv[ci] = v;
          }
          float mx = fmaxf(fmaxf(sv[0], sv[1]), fmaxf(sv[2], sv[3]));
#pragma unroll
          for (int d = 1; d < 16; d <<= 1) mx = fmaxf(mx, __shfl_xor(mx, d));
          float mnew = fmaxf(mrow[mi][j], mx);
          float alpha = __expf(mrow[mi][j] - mnew);
          float rs = 0.f;
          int prow = mi * 16 + lg * 4 + j;
          int swz = ((lg * 4 + j) & 7) << 3;
#pragma unroll
          for (int ci = 0; ci < 4; ++ci) {
            float p = __expf(sv[ci] - mnew);
            rs += p;
            Ps[wv][prow * 64 + ((ci * 16 + l15) ^ swz)] = f2bf(p);
          }
#pragma unroll
          for (int d = 1; d < 16; d <<= 1) rs += __shfl_xor(rs, d);
          lrow[mi][j] = lrow[mi][j] * alpha + rs;
          mrow[mi][j] = mnew;
#pragma unroll
          for (int n = 0; n < 4; ++n) oacc[mi][n][j] *= alpha;
        }

      // ---- O += P V ----
#pragma unroll
      for (int kk = 0; kk < 2; ++kk) {
        int cswz = (kk * 32 + lg * 8) ^ ((l15 & 7) << 3);
        bf16x8 pa0 = *reinterpret_cast<const bf16x8*>(&Ps[wv][(l15) * 64 + cswz]);
        bf16x8 pa1 = *reinterpret_cast<const bf16x8*>(&Ps[wv][(16 + l15) * 64 + cswz]);
#pragma unroll
        for (int n = 0; n < 4; ++n) {
          bf16x8 bv = *reinterpret_cast<const bf16x8*>(&Vs[buf][(n * 16 + l15) * 64 + cswz]);
          oacc[0][n] = __builtin_amdgcn_mfma_f32_16x16x32_bf16(pa0, bv, oacc[0][n], 0, 0, 0);
          oacc[1][n] = __builtin_amdgcn_mfma_f32_16x16x32_bf16(pa1, bv, oacc[1][n], 0, 0, 0);
        }
      }
    }
    __syncthreads();
  }

  // ---- epilogue: ctx [bt][D] bf16 ----
#pragma unroll
  for (int mi = 0; mi < 2; ++mi)
#pragma unroll
    for (int n = 0; n < 4; ++n)
#pragma unroll
      for (int j = 0; j < 4; ++j) {
        int qg = qmin + mi * 16 + lg * 4 + j;
        int hd = n * 16 + l15;
        ctx[(size_t)(b * Tn + qg) * Dn + h * HDn + hd] =
            f2bf(oacc[mi][n][j] / lrow[mi][j]);
      }
}

extern "C" void kernel_launch(void* const* d_in, const int* in_sizes, int n_in,
                              void* d_out, int out_size, void* d_ws, size_t ws_size,
                              hipStream_t stream) {
  const float* x  = (const float*)d_in[0];
  const float* Wq = (const float*)d_in[1];
  const float* Wk = (const float*)d_in[2];
  const float* Wv = (const float*)d_in[3];
  const float* Wo = (const float*)d_in[4];
  const float* bo = (const float*)d_in[5];
  float* out = (float*)d_out;

  unsigned short* ws  = (unsigned short*)d_ws;
  unsigned short* xbf = ws;                  // 4194304 elems
  unsigned short* wT  = ws + 4194304;        // 4 x 1048576
  unsigned short* qb  = ws + 8388608;
  unsigned short* kb  = ws + 12582912;
  unsigned short* vtb = ws + 16777216;       // transposed [b,h,hd,t]
  unsigned short* ctx = ws + 20971520;

  cvt_bf16<<<4096, 256, 0, stream>>>(x, xbf);
  dim3 tb(32, 8);
  transpose_bf16<<<dim3(32, 32), tb, 0, stream>>>(Wq, wT);
  transpose_bf16<<<dim3(32, 32), tb, 0, stream>>>(Wk, wT + 1048576);
  transpose_bf16<<<dim3(32, 32), tb, 0, stream>>>(Wv, wT + 2097152);
  transpose_bf16<<<dim3(32, 32), tb, 0, stream>>>(Wo, wT + 3145728);

  gemm_qkv<<<dim3(32, 8, 3), 256, 0, stream>>>(xbf, wT, qb, kb, vtb);
  attn2<<<512, 256, 0, stream>>>(qb, kb, vtb, ctx);
  gemm_out<<<dim3(32, 8), 256, 0, stream>>>(ctx, wT + 3145728, bo, out);
}

// Round 3
// 149.346 us; speedup vs baseline: 2.0650x; 1.2097x over previous
//
#include <hip/hip_runtime.h>

#define Bn 2
#define Tn 2048
#define Dn 1024
#define Hn 16
#define HDn 64
#define Mn 4096

typedef __attribute__((ext_vector_type(8))) short bf16x8;
typedef __attribute__((ext_vector_type(4))) float f32x4;

__device__ __forceinline__ unsigned short f2bf(float f) {
  unsigned int x = __builtin_bit_cast(unsigned int, f);
  x += 0x7FFFu + ((x >> 16) & 1u);   // round-to-nearest-even
  return (unsigned short)(x >> 16);
}

__device__ __forceinline__ void gload_lds16(const void* g, void* l) {
  __builtin_amdgcn_global_load_lds(
      (const __attribute__((address_space(1))) unsigned int*)g,
      (__attribute__((address_space(3))) unsigned int*)l,
      16, 0, 0);
}

// ---------------- f32 -> bf16 convert (x), vectorized ----------------
__global__ __launch_bounds__(256) void cvt_bf16(const float* __restrict__ in,
                                                unsigned short* __restrict__ out) {
  int i = (blockIdx.x * 256 + threadIdx.x) * 4;
  float4 v = *reinterpret_cast<const float4*>(in + i);
  ushort4 o;
  o.x = f2bf(v.x); o.y = f2bf(v.y); o.z = f2bf(v.z); o.w = f2bf(v.w);
  *reinterpret_cast<ushort4*>(out + i) = o;
}

// ---------------- W[k][n] f32 -> WT[n][k] bf16, LDS-tiled, all 4 in one launch ----------------
__global__ __launch_bounds__(256) void transpose4(const float* __restrict__ W0,
                                                  const float* __restrict__ W1,
                                                  const float* __restrict__ W2,
                                                  const float* __restrict__ W3,
                                                  unsigned short* __restrict__ WT) {
  __shared__ float tile[32][33];
  const int z = blockIdx.z;
  const float* W = (z == 0) ? W0 : (z == 1) ? W1 : (z == 2) ? W2 : W3;
  unsigned short* dst = WT + (size_t)z * 1048576;
  int n0 = blockIdx.x * 32, k0 = blockIdx.y * 32;
  int tx = threadIdx.x, ty = threadIdx.y;   // 32 x 8
#pragma unroll
  for (int r = ty; r < 32; r += 8)
    tile[r][tx] = W[(size_t)(k0 + r) * Dn + n0 + tx];
  __syncthreads();
#pragma unroll
  for (int r = ty; r < 32; r += 8)
    dst[(size_t)(n0 + r) * Dn + k0 + tx] = f2bf(tile[tx][r]);
}

// ---------------- QKV projection GEMM: q/k [b,h,t,hd], v transposed [b,h,hd,t] ----------------
__global__ __launch_bounds__(256) void gemm_qkv(const unsigned short* __restrict__ A,
                                                const unsigned short* __restrict__ WTall,
                                                unsigned short* __restrict__ qb,
                                                unsigned short* __restrict__ kb,
                                                unsigned short* __restrict__ vtb) {
  const int m0 = blockIdx.x * 128;
  const int n0 = blockIdx.y * 128;
  const int z  = blockIdx.z;
  const unsigned short* BT = WTall + (size_t)z * 1048576;

  __shared__ unsigned short As[128 * 32];
  __shared__ unsigned short Bs[128 * 32];

  const int tid  = threadIdx.x;
  const int lane = tid & 63;
  const int wv   = tid >> 6;
  const int wr   = wv >> 1, wc = wv & 1;
  const int l15  = lane & 15, lg = lane >> 4;

  f32x4 acc[4][4];
#pragma unroll
  for (int mi = 0; mi < 4; ++mi)
#pragma unroll
    for (int ni = 0; ni < 4; ++ni)
      acc[mi][ni] = (f32x4){0.f, 0.f, 0.f, 0.f};

  for (int kt = 0; kt < 32; ++kt) {
#pragma unroll
    for (int it = 0; it < 2; ++it) {
      int e = (it * 256 + tid) * 8;
      int r = e >> 5, c = e & 31;
      gload_lds16(A  + (size_t)(m0 + r) * Dn + kt * 32 + c,
                  (char*)As + it * 4096 + wv * 1024);
      gload_lds16(BT + (size_t)(n0 + r) * Dn + kt * 32 + c,
                  (char*)Bs + it * 4096 + wv * 1024);
    }
    __syncthreads();

    bf16x8 af[4], bf[4];
#pragma unroll
    for (int mi = 0; mi < 4; ++mi) {
      int row = wr * 64 + mi * 16 + l15;
      af[mi] = *reinterpret_cast<const bf16x8*>(&As[row * 32 + lg * 8]);
    }
#pragma unroll
    for (int ni = 0; ni < 4; ++ni) {
      int row = wc * 64 + ni * 16 + l15;
      bf[ni] = *reinterpret_cast<const bf16x8*>(&Bs[row * 32 + lg * 8]);
    }
#pragma unroll
    for (int mi = 0; mi < 4; ++mi)
#pragma unroll
      for (int ni = 0; ni < 4; ++ni)
        acc[mi][ni] = __builtin_amdgcn_mfma_f32_16x16x32_bf16(af[mi], bf[ni], acc[mi][ni], 0, 0, 0);
    __syncthreads();
  }

  unsigned short* dst = (z == 0) ? qb : (z == 1) ? kb : vtb;
#pragma unroll
  for (int mi = 0; mi < 4; ++mi)
#pragma unroll
    for (int ni = 0; ni < 4; ++ni)
#pragma unroll
      for (int j = 0; j < 4; ++j) {
        int row = m0 + wr * 64 + mi * 16 + (lg << 2) + j;
        int col = n0 + wc * 64 + ni * 16 + l15;
        int b = row >> 11, t = row & (Tn - 1);
        int h = col >> 6,  hd = col & 63;
        size_t idx = (z == 2)
          ? ((size_t)((b * Hn + h) * HDn + hd)) * Tn + t
          : ((size_t)(b * Hn + h) * Tn + t) * HDn + hd;
        dst[idx] = f2bf(acc[mi][ni][j]);
      }
}

// ---------------- output projection GEMM + bias -> f32 ----------------
__global__ __launch_bounds__(256) void gemm_out(const unsigned short* __restrict__ A,
                                                const unsigned short* __restrict__ BT,
                                                const float* __restrict__ bias,
                                                float* __restrict__ out) {
  const int m0 = blockIdx.x * 128;
  const int n0 = blockIdx.y * 128;

  __shared__ unsigned short As[128 * 32];
  __shared__ unsigned short Bs[128 * 32];

  const int tid  = threadIdx.x;
  const int lane = tid & 63;
  const int wv   = tid >> 6;
  const int wr   = wv >> 1, wc = wv & 1;
  const int l15  = lane & 15, lg = lane >> 4;

  f32x4 acc[4][4];
#pragma unroll
  for (int mi = 0; mi < 4; ++mi)
#pragma unroll
    for (int ni = 0; ni < 4; ++ni)
      acc[mi][ni] = (f32x4){0.f, 0.f, 0.f, 0.f};

  for (int kt = 0; kt < 32; ++kt) {
#pragma unroll
    for (int it = 0; it < 2; ++it) {
      int e = (it * 256 + tid) * 8;
      int r = e >> 5, c = e & 31;
      gload_lds16(A  + (size_t)(m0 + r) * Dn + kt * 32 + c,
                  (char*)As + it * 4096 + wv * 1024);
      gload_lds16(BT + (size_t)(n0 + r) * Dn + kt * 32 + c,
                  (char*)Bs + it * 4096 + wv * 1024);
    }
    __syncthreads();

    bf16x8 af[4], bf[4];
#pragma unroll
    for (int mi = 0; mi < 4; ++mi) {
      int row = wr * 64 + mi * 16 + l15;
      af[mi] = *reinterpret_cast<const bf16x8*>(&As[row * 32 + lg * 8]);
    }
#pragma unroll
    for (int ni = 0; ni < 4; ++ni) {
      int row = wc * 64 + ni * 16 + l15;
      bf[ni] = *reinterpret_cast<const bf16x8*>(&Bs[row * 32 + lg * 8]);
    }
#pragma unroll
    for (int mi = 0; mi < 4; ++mi)
#pragma unroll
      for (int ni = 0; ni < 4; ++ni)
        acc[mi][ni] = __builtin_amdgcn_mfma_f32_16x16x32_bf16(af[mi], bf[ni], acc[mi][ni], 0, 0, 0);
    __syncthreads();
  }

#pragma unroll
  for (int mi = 0; mi < 4; ++mi)
#pragma unroll
    for (int ni = 0; ni < 4; ++ni)
#pragma unroll
      for (int j = 0; j < 4; ++j) {
        int row = m0 + wr * 64 + mi * 16 + (lg << 2) + j;
        int col = n0 + wc * 64 + ni * 16 + l15;
        out[(size_t)row * Dn + col] = acc[mi][ni][j] + bias[col];
      }
}

// ---------------- flash attention v3: 4 waves x 16 q-rows (64 q-rows/block), KVBLK=64 ----------------
// grid: 1024 blocks. head = bid % 32 -> head pinned to XCD head%8. qb = 31 - bid/32 (heavy first).
__global__ __launch_bounds__(256) void attn3(const unsigned short* __restrict__ q,
                                             const unsigned short* __restrict__ k,
                                             const unsigned short* __restrict__ vT,
                                             unsigned short* __restrict__ ctx) {
  __shared__ unsigned short Ks[2][4096];   // [key][hd], col-swizzled
  __shared__ unsigned short Vs[2][4096];   // [hd][key], col-swizzled
  __shared__ unsigned short Ps[4][1024];   // per-wave P [16][64], col-swizzled

  const int tid  = threadIdx.x;
  const int lane = tid & 63;
  const int wv   = tid >> 6;
  const int l15  = lane & 15, lg = lane >> 4;

  const int bid   = blockIdx.x;
  const int head  = bid & 31;
  const int qb    = 31 - (bid >> 5);
  const int qbase = qb * 64;
  const int b = head >> 4, h = head & 15;

  const unsigned short* qh = q  + (size_t)head * Tn * HDn;
  const unsigned short* kh = k  + (size_t)head * Tn * HDn;
  const unsigned short* vh = vT + (size_t)head * HDn * Tn;

  const int qmin = qbase + wv * 16;   // this wave's 16 q-rows

  bf16x8 aq[2];
#pragma unroll
  for (int kc = 0; kc < 2; ++kc)
    aq[kc] = *reinterpret_cast<const bf16x8*>(
        qh + (size_t)(qmin + l15) * HDn + kc * 32 + lg * 8);

  f32x4 oacc[4];
#pragma unroll
  for (int n = 0; n < 4; ++n) oacc[n] = (f32x4){0.f, 0.f, 0.f, 0.f};
  float mrow[4], lrow[4];
#pragma unroll
  for (int j = 0; j < 4; ++j) { mrow[j] = -INFINITY; lrow[j] = 0.f; }

  // stage a 64-key tile of K and V (source pre-swizzled: col ^= (row&7)<<3)
  auto stage = [&](int buf, int k0) {
#pragma unroll
    for (int it = 0; it < 2; ++it) {
      int o = (it * 256 + tid) * 8;
      int row = o >> 6;
      int col = (o & 63) ^ ((row & 7) << 3);
      gload_lds16(kh + (size_t)(k0 + row) * HDn + col,
                  (char*)&Ks[buf][0] + (it * 2048 + wv * 512) * 2);
      gload_lds16(vh + (size_t)row * Tn + k0 + col,
                  (char*)&Vs[buf][0] + (it * 2048 + wv * 512) * 2);
    }
  };

  const int nkt = qb + 1;
  stage(0, 0);
  __syncthreads();

  for (int kt = 0; kt < nkt; ++kt) {
    const int buf = kt & 1;
    const int k0  = kt << 6;
    if (kt + 1 < nkt) stage(buf ^ 1, (kt + 1) << 6);

    // ---- S = Q K^T : 16 x 64 ----
    f32x4 s[4];
#pragma unroll
    for (int ci = 0; ci < 4; ++ci) s[ci] = (f32x4){0.f, 0.f, 0.f, 0.f};
    __builtin_amdgcn_s_setprio(1);
#pragma unroll
    for (int ci = 0; ci < 4; ++ci) {
      int row = ci * 16 + l15;
#pragma unroll
      for (int kc = 0; kc < 2; ++kc) {
        bf16x8 bk = *reinterpret_cast<const bf16x8*>(
            &Ks[buf][row * 64 + ((kc * 32 + lg * 8) ^ ((l15 & 7) << 3))]);
        s[ci] = __builtin_amdgcn_mfma_f32_16x16x32_bf16(aq[kc], bk, s[ci], 0, 0, 0);
      }
    }
    __builtin_amdgcn_s_setprio(0);

    const bool needmask = (k0 + 63 > qmin);
    // ---- online softmax (T13 defer-max, raw-space threshold 64 == scaled 8) ----
#pragma unroll
    for (int j = 0; j < 4; ++j) {
      int qrow = qmin + (lg << 2) + j;
      float sv[4];
#pragma unroll
      for (int ci = 0; ci < 4; ++ci) {
        float v = s[ci][j];
        if (needmask && (k0 + ci * 16 + l15 > qrow)) v = -INFINITY;
        sv[ci] = v;
      }
      float mx = fmaxf(fmaxf(sv[0], sv[1]), fmaxf(sv[2], sv[3]));
#pragma unroll
      for (int d = 1; d < 16; d <<= 1) mx = fmaxf(mx, __shfl_xor(mx, d));
      if (!__all(mx <= mrow[j] + 64.0f)) {
        float mnew = fmaxf(mrow[j], mx);
        float alpha = __expf(0.125f * (mrow[j] - mnew));
        lrow[j] *= alpha;
#pragma unroll
        for (int n = 0; n < 4; ++n) oacc[n][j] *= alpha;
        mrow[j] = mnew;
      }
      float rs = 0.f;
      int prow = (lg << 2) + j;
      int swz = (prow & 7) << 3;
#pragma unroll
      for (int ci = 0; ci < 4; ++ci) {
        float p = __expf(0.125f * (sv[ci] - mrow[j]));
        rs += p;
        Ps[wv][prow * 64 + ((ci * 16 + l15) ^ swz)] = f2bf(p);
      }
#pragma unroll
      for (int d = 1; d < 16; d <<= 1) rs += __shfl_xor(rs, d);
      lrow[j] += rs;
    }

    // ---- O += P V ----
    __builtin_amdgcn_s_setprio(1);
#pragma unroll
    for (int kk = 0; kk < 2; ++kk) {
      int cswz = (kk * 32 + lg * 8) ^ ((l15 & 7) << 3);
      bf16x8 pa = *reinterpret_cast<const bf16x8*>(&Ps[wv][l15 * 64 + cswz]);
#pragma unroll
      for (int n = 0; n < 4; ++n) {
        bf16x8 bv = *reinterpret_cast<const bf16x8*>(&Vs[buf][(n * 16 + l15) * 64 + cswz]);
        oacc[n] = __builtin_amdgcn_mfma_f32_16x16x32_bf16(pa, bv, oacc[n], 0, 0, 0);
      }
    }
    __builtin_amdgcn_s_setprio(0);
    __syncthreads();
  }

  // ---- epilogue ----
#pragma unroll
  for (int n = 0; n < 4; ++n)
#pragma unroll
    for (int j = 0; j < 4; ++j) {
      int qg = qmin + (lg << 2) + j;
      int hd = n * 16 + l15;
      ctx[(size_t)(b * Tn + qg) * Dn + h * HDn + hd] = f2bf(oacc[n][j] / lrow[j]);
    }
}

extern "C" void kernel_launch(void* const* d_in, const int* in_sizes, int n_in,
                              void* d_out, int out_size, void* d_ws, size_t ws_size,
                              hipStream_t stream) {
  const float* x  = (const float*)d_in[0];
  const float* Wq = (const float*)d_in[1];
  const float* Wk = (const float*)d_in[2];
  const float* Wv = (const float*)d_in[3];
  const float* Wo = (const float*)d_in[4];
  const float* bo = (const float*)d_in[5];
  float* out = (float*)d_out;

  unsigned short* ws  = (unsigned short*)d_ws;
  unsigned short* xbf = ws;                  // 4194304 elems
  unsigned short* wT  = ws + 4194304;        // 4 x 1048576
  unsigned short* qb  = ws + 8388608;
  unsigned short* kb  = ws + 12582912;
  unsigned short* vtb = ws + 16777216;       // transposed [b,h,hd,t]
  unsigned short* ctx = ws + 20971520;

  cvt_bf16<<<4096, 256, 0, stream>>>(x, xbf);
  transpose4<<<dim3(32, 32, 4), dim3(32, 8), 0, stream>>>(Wq, Wk, Wv, Wo, wT);

  gemm_qkv<<<dim3(32, 8, 3), 256, 0, stream>>>(xbf, wT, qb, kb, vtb);
  attn3<<<1024, 256, 0, stream>>>(qb, kb, vtb, ctx);
  gemm_out<<<dim3(32, 8), 256, 0, stream>>>(ctx, wT + 3145728, bo, out);
}

// Round 4
// 128.178 us; speedup vs baseline: 2.4061x; 1.1652x over previous
//
#include <hip/hip_runtime.h>

#define Bn 2
#define Tn 2048
#define Dn 1024
#define Hn 16
#define HDn 64
#define Mn 4096

typedef __attribute__((ext_vector_type(8))) short bf16x8;
typedef __attribute__((ext_vector_type(4))) float f32x4;

__device__ __forceinline__ unsigned short f2bf(float f) {
  unsigned int x = __builtin_bit_cast(unsigned int, f);
  x += 0x7FFFu + ((x >> 16) & 1u);   // round-to-nearest-even
  return (unsigned short)(x >> 16);
}

__device__ __forceinline__ void gload_lds16(const void* g, void* l) {
  __builtin_amdgcn_global_load_lds(
      (const __attribute__((address_space(1))) unsigned int*)g,
      (__attribute__((address_space(3))) unsigned int*)l,
      16, 0, 0);
}

// ---------------- f32 -> bf16 convert (x), vectorized ----------------
__global__ __launch_bounds__(256) void cvt_bf16(const float* __restrict__ in,
                                                unsigned short* __restrict__ out) {
  int i = (blockIdx.x * 256 + threadIdx.x) * 4;
  float4 v = *reinterpret_cast<const float4*>(in + i);
  ushort4 o;
  o.x = f2bf(v.x); o.y = f2bf(v.y); o.z = f2bf(v.z); o.w = f2bf(v.w);
  *reinterpret_cast<ushort4*>(out + i) = o;
}

// ---------------- W[k][n] f32 -> WT[n][k] bf16, LDS-tiled, all 4 in one launch ----------------
__global__ __launch_bounds__(256) void transpose4(const float* __restrict__ W0,
                                                  const float* __restrict__ W1,
                                                  const float* __restrict__ W2,
                                                  const float* __restrict__ W3,
                                                  unsigned short* __restrict__ WT) {
  __shared__ float tile[32][33];
  const int z = blockIdx.z;
  const float* W = (z == 0) ? W0 : (z == 1) ? W1 : (z == 2) ? W2 : W3;
  unsigned short* dst = WT + (size_t)z * 1048576;
  int n0 = blockIdx.x * 32, k0 = blockIdx.y * 32;
  int tx = threadIdx.x, ty = threadIdx.y;   // 32 x 8
#pragma unroll
  for (int r = ty; r < 32; r += 8)
    tile[r][tx] = W[(size_t)(k0 + r) * Dn + n0 + tx];
  __syncthreads();
#pragma unroll
  for (int r = ty; r < 32; r += 8)
    dst[(size_t)(n0 + r) * Dn + k0 + tx] = f2bf(tile[tx][r]);
}

// ---------------- QKV projection GEMM: q/k [b,h,t,hd], v transposed [b,h,hd,t] ----------------
__global__ __launch_bounds__(256) void gemm_qkv(const unsigned short* __restrict__ A,
                                                const unsigned short* __restrict__ WTall,
                                                unsigned short* __restrict__ qb,
                                                unsigned short* __restrict__ kb,
                                                unsigned short* __restrict__ vtb) {
  const int m0 = blockIdx.x * 128;
  const int n0 = blockIdx.y * 128;
  const int z  = blockIdx.z;
  const unsigned short* BT = WTall + (size_t)z * 1048576;

  __shared__ unsigned short As[128 * 32];
  __shared__ unsigned short Bs[128 * 32];

  const int tid  = threadIdx.x;
  const int lane = tid & 63;
  const int wv   = tid >> 6;
  const int wr   = wv >> 1, wc = wv & 1;
  const int l15  = lane & 15, lg = lane >> 4;

  f32x4 acc[4][4];
#pragma unroll
  for (int mi = 0; mi < 4; ++mi)
#pragma unroll
    for (int ni = 0; ni < 4; ++ni)
      acc[mi][ni] = (f32x4){0.f, 0.f, 0.f, 0.f};

  for (int kt = 0; kt < 32; ++kt) {
#pragma unroll
    for (int it = 0; it < 2; ++it) {
      int e = (it * 256 + tid) * 8;
      int r = e >> 5, c = e & 31;
      gload_lds16(A  + (size_t)(m0 + r) * Dn + kt * 32 + c,
                  (char*)As + it * 4096 + wv * 1024);
      gload_lds16(BT + (size_t)(n0 + r) * Dn + kt * 32 + c,
                  (char*)Bs + it * 4096 + wv * 1024);
    }
    __syncthreads();

    bf16x8 af[4], bf[4];
#pragma unroll
    for (int mi = 0; mi < 4; ++mi) {
      int row = wr * 64 + mi * 16 + l15;
      af[mi] = *reinterpret_cast<const bf16x8*>(&As[row * 32 + lg * 8]);
    }
#pragma unroll
    for (int ni = 0; ni < 4; ++ni) {
      int row = wc * 64 + ni * 16 + l15;
      bf[ni] = *reinterpret_cast<const bf16x8*>(&Bs[row * 32 + lg * 8]);
    }
#pragma unroll
    for (int mi = 0; mi < 4; ++mi)
#pragma unroll
      for (int ni = 0; ni < 4; ++ni)
        acc[mi][ni] = __builtin_amdgcn_mfma_f32_16x16x32_bf16(af[mi], bf[ni], acc[mi][ni], 0, 0, 0);
    __syncthreads();
  }

  unsigned short* dst = (z == 0) ? qb : (z == 1) ? kb : vtb;
#pragma unroll
  for (int mi = 0; mi < 4; ++mi)
#pragma unroll
    for (int ni = 0; ni < 4; ++ni)
#pragma unroll
      for (int j = 0; j < 4; ++j) {
        int row = m0 + wr * 64 + mi * 16 + (lg << 2) + j;
        int col = n0 + wc * 64 + ni * 16 + l15;
        int b = row >> 11, t = row & (Tn - 1);
        int h = col >> 6,  hd = col & 63;
        size_t idx = (z == 2)
          ? ((size_t)((b * Hn + h) * HDn + hd)) * Tn + t
          : ((size_t)(b * Hn + h) * Tn + t) * HDn + hd;
        dst[idx] = f2bf(acc[mi][ni][j]);
      }
}

// ---------------- output projection GEMM + bias -> f32 ----------------
__global__ __launch_bounds__(256) void gemm_out(const unsigned short* __restrict__ A,
                                                const unsigned short* __restrict__ BT,
                                                const float* __restrict__ bias,
                                                float* __restrict__ out) {
  const int m0 = blockIdx.x * 128;
  const int n0 = blockIdx.y * 128;

  __shared__ unsigned short As[128 * 32];
  __shared__ unsigned short Bs[128 * 32];

  const int tid  = threadIdx.x;
  const int lane = tid & 63;
  const int wv   = tid >> 6;
  const int wr   = wv >> 1, wc = wv & 1;
  const int l15  = lane & 15, lg = lane >> 4;

  f32x4 acc[4][4];
#pragma unroll
  for (int mi = 0; mi < 4; ++mi)
#pragma unroll
    for (int ni = 0; ni < 4; ++ni)
      acc[mi][ni] = (f32x4){0.f, 0.f, 0.f, 0.f};

  for (int kt = 0; kt < 32; ++kt) {
#pragma unroll
    for (int it = 0; it < 2; ++it) {
      int e = (it * 256 + tid) * 8;
      int r = e >> 5, c = e & 31;
      gload_lds16(A  + (size_t)(m0 + r) * Dn + kt * 32 + c,
                  (char*)As + it * 4096 + wv * 1024);
      gload_lds16(BT + (size_t)(n0 + r) * Dn + kt * 32 + c,
                  (char*)Bs + it * 4096 + wv * 1024);
    }
    __syncthreads();

    bf16x8 af[4], bf[4];
#pragma unroll
    for (int mi = 0; mi < 4; ++mi) {
      int row = wr * 64 + mi * 16 + l15;
      af[mi] = *reinterpret_cast<const bf16x8*>(&As[row * 32 + lg * 8]);
    }
#pragma unroll
    for (int ni = 0; ni < 4; ++ni) {
      int row = wc * 64 + ni * 16 + l15;
      bf[ni] = *reinterpret_cast<const bf16x8*>(&Bs[row * 32 + lg * 8]);
    }
#pragma unroll
    for (int mi = 0; mi < 4; ++mi)
#pragma unroll
      for (int ni = 0; ni < 4; ++ni)
        acc[mi][ni] = __builtin_amdgcn_mfma_f32_16x16x32_bf16(af[mi], bf[ni], acc[mi][ni], 0, 0, 0);
    __syncthreads();
  }

#pragma unroll
  for (int mi = 0; mi < 4; ++mi)
#pragma unroll
    for (int ni = 0; ni < 4; ++ni)
#pragma unroll
      for (int j = 0; j < 4; ++j) {
        int row = m0 + wr * 64 + mi * 16 + (lg << 2) + j;
        int col = n0 + wc * 64 + ni * 16 + l15;
        out[(size_t)row * Dn + col] = acc[mi][ni][j] + bias[col];
      }
}

// ---------------- flash attention v4: swapped-operand in-register softmax ----------------
// 512 blocks, 4 waves. Block handles q-block pair {p, 31-p} (64 rows each) -> uniform 33
// set-tiles/block. head = bid % 32 pins each head's K/V to one XCD L2.
// Swapped QK^T: S^T = mfma(K_frag, Q_frag) -> lane owns q-row = qmin + (lane&15).
// Swapped PV:   O^T = mfma(V_frag, P_frag) -> oacc[n][r] = O[q=qmin+l15][d=n*16+4*lg+r].
__global__ __launch_bounds__(256, 2) void attn4(const unsigned short* __restrict__ q,
                                                const unsigned short* __restrict__ k,
                                                const unsigned short* __restrict__ vT,
                                                unsigned short* __restrict__ ctx) {
  __shared__ unsigned short Ks[2][4096];   // [key][hd], col-swizzled
  __shared__ unsigned short Vs[2][4096];   // [hd][key], col-swizzled
  __shared__ unsigned short PsL[4][1024];  // per-wave P^ [16 q][64 k], col-swizzled
  __shared__ unsigned short PsH[4][1024];

  const int tid  = threadIdx.x;
  const int lane = tid & 63;
  const int wv   = tid >> 6;
  const int l15  = lane & 15, lg = lane >> 4;

  const int bid  = blockIdx.x;
  const int head = bid & 31;
  const int pr   = bid >> 5;          // 0..15
  const int qlo  = pr, qhi = 31 - pr;
  const int b = head >> 4, h = head & 15;

  const unsigned short* qh = q  + (size_t)head * Tn * HDn;
  const unsigned short* kh = k  + (size_t)head * Tn * HDn;
  const unsigned short* vh = vT + (size_t)head * HDn * Tn;

  const int qminL = qlo * 64 + wv * 16;
  const int qminH = qhi * 64 + wv * 16;

  bf16x8 aqL[2], aqH[2];
#pragma unroll
  for (int kc = 0; kc < 2; ++kc) {
    aqL[kc] = *reinterpret_cast<const bf16x8*>(qh + (size_t)(qminL + l15) * HDn + kc * 32 + lg * 8);
    aqH[kc] = *reinterpret_cast<const bf16x8*>(qh + (size_t)(qminH + l15) * HDn + kc * 32 + lg * 8);
  }

  f32x4 oL[4], oH[4];
#pragma unroll
  for (int n = 0; n < 4; ++n) { oL[n] = (f32x4){0.f,0.f,0.f,0.f}; oH[n] = (f32x4){0.f,0.f,0.f,0.f}; }
  float mL = -INFINITY, lL = 0.f, mH = -INFINITY, lH = 0.f;

  const float SC = 0.18033688011112042f;   // 0.125 * log2(e)
  const int swz = (l15 & 7) << 3;

  auto stage = [&](int buf, int k0) {
#pragma unroll
    for (int it = 0; it < 2; ++it) {
      int o = (it * 256 + tid) * 8;
      int row = o >> 6;
      int col = (o & 63) ^ ((row & 7) << 3);
      gload_lds16(kh + (size_t)(k0 + row) * HDn + col,
                  (char*)&Ks[buf][0] + (it * 2048 + wv * 512) * 2);
      gload_lds16(vh + (size_t)row * Tn + k0 + col,
                  (char*)&Vs[buf][0] + (it * 2048 + wv * 512) * 2);
    }
  };

  auto computeSet = [&](int qmin, const bf16x8 (&aq)[2], f32x4 (&oacc)[4],
                        float& m, float& l, unsigned short* PsW, int k0, int buf) {
    // ---- S^T = K Q^T (swapped): 16 q-cols x 64 k-rows ----
    f32x4 s[4];
#pragma unroll
    for (int ci = 0; ci < 4; ++ci) s[ci] = (f32x4){0.f, 0.f, 0.f, 0.f};
    __builtin_amdgcn_s_setprio(1);
#pragma unroll
    for (int ci = 0; ci < 4; ++ci) {
      int row = ci * 16 + l15;
#pragma unroll
      for (int kc = 0; kc < 2; ++kc) {
        bf16x8 bk = *reinterpret_cast<const bf16x8*>(
            &Ks[buf][row * 64 + ((kc * 32 + lg * 8) ^ swz)]);
        s[ci] = __builtin_amdgcn_mfma_f32_16x16x32_bf16(bk, aq[kc], s[ci], 0, 0, 0);
      }
    }
    __builtin_amdgcn_s_setprio(0);

    // ---- lane-local softmax: lane owns q = qmin+l15; k = k0 + 16*ci + 4*lg + r ----
    const int mrel = qmin + l15 - k0 - 4 * lg;      // masked iff 16*ci + r > mrel
    const bool needmask = (k0 + 63 > qmin);
    float sv[4][4];
#pragma unroll
    for (int ci = 0; ci < 4; ++ci)
#pragma unroll
      for (int r = 0; r < 4; ++r) {
        float v = s[ci][r] * SC;
        if (needmask && (16 * ci + r > mrel)) v = -INFINITY;
        sv[ci][r] = v;
      }
    float a0 = fmaxf(fmaxf(sv[0][0], sv[0][1]), fmaxf(sv[0][2], sv[0][3]));
    float a1 = fmaxf(fmaxf(sv[1][0], sv[1][1]), fmaxf(sv[1][2], sv[1][3]));
    float a2 = fmaxf(fmaxf(sv[2][0], sv[2][1]), fmaxf(sv[2][2], sv[2][3]));
    float a3 = fmaxf(fmaxf(sv[3][0], sv[3][1]), fmaxf(sv[3][2], sv[3][3]));
    float mx = fmaxf(fmaxf(a0, a1), fmaxf(a2, a3));
    mx = fmaxf(mx, __shfl_xor(mx, 16));
    mx = fmaxf(mx, __shfl_xor(mx, 32));
    if (!__all(mx <= m + 11.5f)) {      // T13 defer-max (8 nats = 11.54 in log2/8 units)
      float mn = fmaxf(m, mx);
      float alpha = exp2f(m - mn);
      l *= alpha;
#pragma unroll
      for (int n = 0; n < 4; ++n) oacc[n] *= alpha;
      m = mn;
    }
    float rs = 0.f;
#pragma unroll
    for (int ci = 0; ci < 4; ++ci) {
      float p0 = exp2f(sv[ci][0] - m);
      float p1 = exp2f(sv[ci][1] - m);
      float p2 = exp2f(sv[ci][2] - m);
      float p3 = exp2f(sv[ci][3] - m);
      rs += (p0 + p1) + (p2 + p3);
      ushort4 pk = { f2bf(p0), f2bf(p1), f2bf(p2), f2bf(p3) };
      *reinterpret_cast<ushort4*>(&PsW[l15 * 64 + ((ci * 16 + 4 * lg) ^ swz)]) = pk;
    }
    rs += __shfl_xor(rs, 16);
    rs += __shfl_xor(rs, 32);
    l += rs;

    // ---- O^T += V^T P^T (swapped) ----
    __builtin_amdgcn_s_setprio(1);
#pragma unroll
    for (int kk = 0; kk < 2; ++kk) {
      bf16x8 pa = *reinterpret_cast<const bf16x8*>(&PsW[l15 * 64 + ((kk * 32 + lg * 8) ^ swz)]);
#pragma unroll
      for (int n = 0; n < 4; ++n) {
        bf16x8 bv = *reinterpret_cast<const bf16x8*>(
            &Vs[buf][(n * 16 + l15) * 64 + ((kk * 32 + lg * 8) ^ swz)]);
        oacc[n] = __builtin_amdgcn_mfma_f32_16x16x32_bf16(bv, pa, oacc[n], 0, 0, 0);
      }
    }
    __builtin_amdgcn_s_setprio(0);
  };

  const int nkt = qhi + 1;
  stage(0, 0);
  __syncthreads();

  for (int kt = 0; kt < nkt; ++kt) {
    const int buf = kt & 1;
    const int k0  = kt << 6;
    if (kt + 1 < nkt) stage(buf ^ 1, (kt + 1) << 6);
    computeSet(qminH, aqH, oH, mH, lH, &PsH[wv][0], k0, buf);
    if (kt <= qlo)
      computeSet(qminL, aqL, oL, mL, lL, &PsL[wv][0], k0, buf);
    __syncthreads();
  }

  // ---- epilogue: ctx [bt][D] bf16; lane q = qmin+l15, d = n*16+4*lg+r ----
  auto epilogue = [&](int qmin, f32x4 (&oacc)[4], float l) {
    float inv = 1.0f / l;
#pragma unroll
    for (int n = 0; n < 4; ++n) {
      ushort4 o;
      o.x = f2bf(oacc[n][0] * inv);
      o.y = f2bf(oacc[n][1] * inv);
      o.z = f2bf(oacc[n][2] * inv);
      o.w = f2bf(oacc[n][3] * inv);
      *reinterpret_cast<ushort4*>(
          &ctx[(size_t)(b * Tn + qmin + l15) * Dn + h * HDn + n * 16 + 4 * lg]) = o;
    }
  };
  epilogue(qminL, oL, lL);
  epilogue(qminH, oH, lH);
}

extern "C" void kernel_launch(void* const* d_in, const int* in_sizes, int n_in,
                              void* d_out, int out_size, void* d_ws, size_t ws_size,
                              hipStream_t stream) {
  const float* x  = (const float*)d_in[0];
  const float* Wq = (const float*)d_in[1];
  const float* Wk = (const float*)d_in[2];
  const float* Wv = (const float*)d_in[3];
  const float* Wo = (const float*)d_in[4];
  const float* bo = (const float*)d_in[5];
  float* out = (float*)d_out;

  unsigned short* ws  = (unsigned short*)d_ws;
  unsigned short* xbf = ws;                  // 4194304 elems
  unsigned short* wT  = ws + 4194304;        // 4 x 1048576
  unsigned short* qb  = ws + 8388608;
  unsigned short* kb  = ws + 12582912;
  unsigned short* vtb = ws + 16777216;       // transposed [b,h,hd,t]
  unsigned short* ctx = ws + 20971520;

  cvt_bf16<<<4096, 256, 0, stream>>>(x, xbf);
  transpose4<<<dim3(32, 32, 4), dim3(32, 8), 0, stream>>>(Wq, Wk, Wv, Wo, wT);

  gemm_qkv<<<dim3(32, 8, 3), 256, 0, stream>>>(xbf, wT, qb, kb, vtb);
  attn4<<<512, 256, 0, stream>>>(qb, kb, vtb, ctx);
  gemm_out<<<dim3(32, 8), 256, 0, stream>>>(ctx, wT + 3145728, bo, out);
}